// Round 3
// baseline (1865.760 us; speedup 1.0000x reference)
//
#include <hip/hip_runtime.h>
#include <hip/hip_bf16.h>
#include <stdint.h>

#define NIN    100000
#define NOUT   200000
#define KOFF   27
#define C      64
#define NPAIR  (KOFF * NIN)            // 2,700,000
#define EPS    1e-5f
#define NB_SCAN ((NOUT + 255) / 256)   // 782

// ---------------- Phase A: dense GEMM  P_chunk[lk] = feats @ W[k0+lk] ------
// One wave per (local k, row). lane = out channel; W column in 64 VGPRs.
__global__ __launch_bounds__(256)
void gemm_p_kernel(const float* __restrict__ feats,
                   const float* __restrict__ weight,
                   __hip_bfloat16* __restrict__ P, int k0)
{
    const int lk   = blockIdx.y;
    const int k    = k0 + lk;
    const int lane = threadIdx.x & 63;
    const int wave = threadIdx.x >> 6;
    const int wavesInGrid = gridDim.x * 4;
    const int waveId      = blockIdx.x * 4 + wave;

    const float* wk = weight + (size_t)k * C * C + lane;
    float w[C];
    #pragma unroll
    for (int ci = 0; ci < C; ++ci) w[ci] = wk[(size_t)ci * C];

    __hip_bfloat16* Pk = P + (size_t)lk * NIN * C;

    for (int r = waveId; r < NIN; r += wavesInGrid) {
        const float4* frow = reinterpret_cast<const float4*>(feats + (size_t)r * C);
        float acc = 0.0f;
        #pragma unroll
        for (int j = 0; j < C / 4; ++j) {
            float4 f = frow[j];                       // broadcast load
            acc = fmaf(f.x, w[4 * j + 0], acc);
            acc = fmaf(f.y, w[4 * j + 1], acc);
            acc = fmaf(f.z, w[4 * j + 2], acc);
            acc = fmaf(f.w, w[4 * j + 3], acc);
        }
        Pk[(size_t)r * C + lane] = __float2bfloat16(acc);
    }
}

// ---------------- Phase B: per-group CSR reverse maps (built in ONE pass) --
// counts/cursor: [G][NOUT] (aliased), offsets: [G][NOUT+1], blocksums: [G][1024]
__global__ __launch_bounds__(256)
void count_all_kernel(const int* __restrict__ out_idx, int* __restrict__ counts,
                      int kpg)
{
    int t = blockIdx.x * 256 + threadIdx.x;
    if (t < NPAIR) {
        int k = t / NIN;
        int g = k / kpg;
        atomicAdd(&counts[(size_t)g * NOUT + out_idx[t]], 1);
    }
}

__global__ __launch_bounds__(256)
void scan1_kernel(const int* __restrict__ counts, int* __restrict__ offsets,
                  int* __restrict__ blocksums)
{
    __shared__ int s[256];
    const int g   = blockIdx.y;
    const int t   = threadIdx.x;
    const int row = blockIdx.x * 256 + t;
    int v = (row < NOUT) ? counts[(size_t)g * NOUT + row] : 0;
    s[t] = v;
    __syncthreads();
    for (int off = 1; off < 256; off <<= 1) {
        int x = (t >= off) ? s[t - off] : 0;
        __syncthreads();
        s[t] += x;
        __syncthreads();
    }
    if (row < NOUT) offsets[(size_t)g * (NOUT + 1) + row] = s[t] - v;
    if (t == 255) blocksums[g * 1024 + blockIdx.x] = s[255];
}

__global__ __launch_bounds__(1024)
void scan2_kernel(int* __restrict__ blocksums, int* __restrict__ offsets)
{
    __shared__ int s[1024];
    const int g = blockIdx.x;
    const int t = threadIdx.x;
    int v = (t < NB_SCAN) ? blocksums[g * 1024 + t] : 0;
    s[t] = v;
    __syncthreads();
    for (int off = 1; off < 1024; off <<= 1) {
        int x = (t >= off) ? s[t - off] : 0;
        __syncthreads();
        s[t] += x;
        __syncthreads();
    }
    if (t < NB_SCAN) blocksums[g * 1024 + t] = s[t] - v;       // exclusive
    if (t == NB_SCAN - 1) offsets[(size_t)g * (NOUT + 1) + NOUT] = s[t];
}

__global__ __launch_bounds__(256)
void scan3_kernel(int* __restrict__ offsets, const int* __restrict__ blocksums,
                  int* __restrict__ cursor)
{
    const int g   = blockIdx.y;
    const int row = blockIdx.x * 256 + threadIdx.x;
    if (row < NOUT) {
        int o = offsets[(size_t)g * (NOUT + 1) + row] + blocksums[g * 1024 + blockIdx.x];
        offsets[(size_t)g * (NOUT + 1) + row] = o;
        cursor[(size_t)g * NOUT + row]        = o;
    }
}

__global__ __launch_bounds__(256)
void fill_all_kernel(const int* __restrict__ in_idx, const int* __restrict__ out_idx,
                     int* __restrict__ cursor, int* __restrict__ pairlist, int kpg)
{
    int t = blockIdx.x * 256 + threadIdx.x;
    if (t < NPAIR) {
        int k  = t / NIN;
        int g  = k / kpg;
        int oi = out_idx[t];
        int pos = atomicAdd(&cursor[(size_t)g * NOUT + oi], 1);
        // group-local P row: (k - g*kpg)*NIN + ii
        pairlist[(size_t)g * kpg * NIN + pos] = (k - g * kpg) * NIN + in_idx[t];
    }
}

// ---------------- Phase C: gather-reduce (+accumulate) (+BN+ReLU last) -----
// 32 threads per output row; each owns a bf16x2 channel pair.
__global__ __launch_bounds__(256)
void gather_accum_kernel(const uint32_t* __restrict__ P32,
                         const int* __restrict__ offsets,
                         const int* __restrict__ pairlist,
                         const float* __restrict__ gamma,
                         const float* __restrict__ beta,
                         const float* __restrict__ mean,
                         const float* __restrict__ var,
                         float* __restrict__ out,
                         int accumulate, int finalize)
{
    int tid = blockIdx.x * 256 + threadIdx.x;
    int row = tid >> 5;
    int cp  = tid & 31;
    if (row >= NOUT) return;

    const int beg = offsets[row];
    const int end = offsets[row + 1];

    float a0 = 0.f, a1 = 0.f;
    int j = beg;
    for (; j + 1 < end; j += 2) {                    // 2 loads in flight
        int p0 = pairlist[j];
        int p1 = pairlist[j + 1];
        uint32_t u0 = P32[(size_t)p0 * 32 + cp];
        uint32_t u1 = P32[(size_t)p1 * 32 + cp];
        a0 += __uint_as_float(u0 << 16);
        a1 += __uint_as_float(u0 & 0xffff0000u);
        a0 += __uint_as_float(u1 << 16);
        a1 += __uint_as_float(u1 & 0xffff0000u);
    }
    if (j < end) {
        uint32_t u0 = P32[(size_t)pairlist[j] * 32 + cp];
        a0 += __uint_as_float(u0 << 16);
        a1 += __uint_as_float(u0 & 0xffff0000u);
    }

    float2* out2 = reinterpret_cast<float2*>(out);
    const size_t oidx = (size_t)row * 32 + cp;
    if (accumulate) {
        float2 v = out2[oidx];
        a0 += v.x;
        a1 += v.y;
    }
    if (finalize) {
        const int c0 = cp * 2;
        float s0 = gamma[c0]     * rsqrtf(var[c0]     + EPS);
        float s1 = gamma[c0 + 1] * rsqrtf(var[c0 + 1] + EPS);
        float y0 = fmaf(a0, s0, beta[c0]     - mean[c0]     * s0);
        float y1 = fmaf(a1, s1, beta[c0 + 1] - mean[c0 + 1] * s1);
        a0 = y0 > 0.f ? y0 : 0.f;
        a1 = y1 > 0.f ? y1 : 0.f;
    }
    out2[oidx] = make_float2(a0, a1);
}

// ---------------- Fallback (round-1 atomic path) ---------------------------
__global__ __launch_bounds__(256)
void conv_scatter_kernel(const float* __restrict__ feats,
                         const float* __restrict__ weight,
                         const int*   __restrict__ in_idx,
                         const int*   __restrict__ out_idx,
                         float*       __restrict__ out)
{
    const int k    = blockIdx.y;
    const int lane = threadIdx.x & 63;
    const int wave = threadIdx.x >> 6;
    const int wavesInGrid = gridDim.x * 4;
    const int waveId      = blockIdx.x * 4 + wave;

    const float* wk = weight + (size_t)k * C * C + lane;
    float w[C];
    #pragma unroll
    for (int ci = 0; ci < C; ++ci) w[ci] = wk[(size_t)ci * C];

    const int* ii_k = in_idx  + (size_t)k * NIN;
    const int* oi_k = out_idx + (size_t)k * NIN;

    for (int r = waveId; r < NIN; r += wavesInGrid) {
        const int ii = ii_k[r];
        const int oi = oi_k[r];
        const float4* frow = reinterpret_cast<const float4*>(feats + (size_t)ii * C);
        float acc = 0.0f;
        #pragma unroll
        for (int j = 0; j < C / 4; ++j) {
            float4 f = frow[j];
            acc = fmaf(f.x, w[4 * j + 0], acc);
            acc = fmaf(f.y, w[4 * j + 1], acc);
            acc = fmaf(f.z, w[4 * j + 2], acc);
            acc = fmaf(f.w, w[4 * j + 3], acc);
        }
        atomicAdd(out + (size_t)oi * C + lane, acc);
    }
}

__global__ __launch_bounds__(256)
void bn_relu_kernel(float* __restrict__ out,
                    const float* __restrict__ gamma,
                    const float* __restrict__ beta,
                    const float* __restrict__ mean,
                    const float* __restrict__ var)
{
    const int total4 = NOUT * C / 4;
    int idx = blockIdx.x * blockDim.x + threadIdx.x;
    if (idx >= total4) return;
    const int c0 = (idx * 4) & (C - 1);
    float sc[4], sh[4];
    #pragma unroll
    for (int j = 0; j < 4; ++j) {
        const int c  = c0 + j;
        const float s = gamma[c] * rsqrtf(var[c] + EPS);
        sc[j] = s;
        sh[j] = beta[c] - mean[c] * s;
    }
    float4* p = reinterpret_cast<float4*>(out) + idx;
    float4 v = *p;
    v.x = fmaf(v.x, sc[0], sh[0]); v.x = v.x > 0.f ? v.x : 0.f;
    v.y = fmaf(v.y, sc[1], sh[1]); v.y = v.y > 0.f ? v.y : 0.f;
    v.z = fmaf(v.z, sc[2], sh[2]); v.z = v.z > 0.f ? v.z : 0.f;
    v.w = fmaf(v.w, sc[3], sh[3]); v.w = v.w > 0.f ? v.w : 0.f;
    *p = v;
}

// ---------------------------------------------------------------------------
extern "C" void kernel_launch(void* const* d_in, const int* in_sizes, int n_in,
                              void* d_out, int out_size, void* d_ws, size_t ws_size,
                              hipStream_t stream) {
    const float* feats   = (const float*)d_in[0];
    const float* weight  = (const float*)d_in[1];
    const int*   in_idx  = (const int*)  d_in[2];
    const int*   out_idx = (const int*)  d_in[3];
    const float* gamma   = (const float*)d_in[4];
    const float* beta    = (const float*)d_in[5];
    const float* rmean   = (const float*)d_in[6];
    const float* rvar    = (const float*)d_in[7];
    float* out = (float*)d_out;

    auto align = [](size_t x) { return (x + 255) & ~(size_t)255; };

    // Pick largest kpg (offsets per group) <= 9 whose buffers fit ws_size.
    // Cap 9 keeps P_chunk <= 115 MB (L3-resident for the random gather).
    int kpg = 0, G = 0;
    size_t oCnt = 0, oOff = 0, oBlk = 0, oPair = 0, oP = 0;
    for (int t = 9; t >= 1; --t) {
        int g = (KOFF + t - 1) / t;
        size_t a = 0;
        size_t c_ = a; a += align((size_t)g * NOUT * 4);          // counts/cursor
        size_t f_ = a; a += align((size_t)g * (NOUT + 1) * 4);    // offsets
        size_t b_ = a; a += align((size_t)g * 1024 * 4);          // blocksums
        size_t p_ = a; a += align((size_t)NPAIR * 4);             // pairlist
        size_t q_ = a; a += align((size_t)t * NIN * C * 2);       // P_chunk bf16
        if (a <= ws_size) {
            kpg = t; G = g; oCnt = c_; oOff = f_; oBlk = b_; oPair = p_; oP = q_;
            break;
        }
    }

    if (kpg == 0) {
        // Fallback: atomic-scatter path
        hipMemsetAsync(out, 0, (size_t)out_size * sizeof(float), stream);
        dim3 grid(512, KOFF);
        conv_scatter_kernel<<<grid, 256, 0, stream>>>(feats, weight, in_idx, out_idx, out);
        const int total4 = NOUT * C / 4;
        bn_relu_kernel<<<(total4 + 255) / 256, 256, 0, stream>>>(out, gamma, beta, rmean, rvar);
        return;
    }

    char* ws = (char*)d_ws;
    int* counts   = (int*)(ws + oCnt);    // reused as cursor after scan1
    int* offsets  = (int*)(ws + oOff);
    int* blksums  = (int*)(ws + oBlk);
    int* pairlist = (int*)(ws + oPair);
    __hip_bfloat16* P = (__hip_bfloat16*)(ws + oP);

    // --- Build all G CSR reverse maps in one pass ---
    hipMemsetAsync(counts, 0, (size_t)G * NOUT * sizeof(int), stream);
    {
        int nb = (NPAIR + 255) / 256;
        count_all_kernel<<<nb, 256, 0, stream>>>(out_idx, counts, kpg);
        dim3 gs(NB_SCAN, G);
        scan1_kernel<<<gs, 256, 0, stream>>>(counts, offsets, blksums);
        scan2_kernel<<<G, 1024, 0, stream>>>(blksums, offsets);
        scan3_kernel<<<gs, 256, 0, stream>>>(offsets, blksums, counts /*cursor*/);
        fill_all_kernel<<<nb, 256, 0, stream>>>(in_idx, out_idx, counts, pairlist, kpg);
    }

    // --- Per-group: GEMM chunk, then gather-accumulate into out ---
    const int gatherBlocks = (NOUT * 32 + 255) / 256;
    for (int g = 0; g < G; ++g) {
        const int k0   = g * kpg;
        const int kcnt = (k0 + kpg <= KOFF) ? kpg : (KOFF - k0);

        dim3 grid(512, kcnt);
        gemm_p_kernel<<<grid, 256, 0, stream>>>(feats, weight, P, k0);

        gather_accum_kernel<<<gatherBlocks, 256, 0, stream>>>(
            (const uint32_t*)P,
            offsets + (size_t)g * (NOUT + 1),
            pairlist + (size_t)g * kpg * NIN,
            gamma, beta, rmean, rvar, out,
            /*accumulate=*/(g > 0), /*finalize=*/(g == G - 1));
    }
}

// Round 4
// 586.862 us; speedup vs baseline: 3.1792x; 3.1792x over previous
//
#include <hip/hip_runtime.h>
#include <hip/hip_bf16.h>
#include <stdint.h>

#define NIN    100000
#define NOUT   200000
#define KOFF   27
#define C      64
#define NPAIR  (KOFF * NIN)            // 2,700,000
#define EPS    1e-5f
#define NB_SCAN ((NOUT + 255) / 256)   // 782

typedef __attribute__((ext_vector_type(8))) short bf16x8;
typedef __attribute__((ext_vector_type(4))) float f32x4;

// ---------------- fp32 -> bf16 conversion (8 elems / thread) ---------------
__global__ __launch_bounds__(256)
void cvt_bf16_kernel(const float* __restrict__ src, ushort* __restrict__ dst, int n8)
{
    int t = blockIdx.x * 256 + threadIdx.x;
    if (t >= n8) return;
    const float4* s4 = reinterpret_cast<const float4*>(src) + (size_t)t * 2;
    float4 a = s4[0], b = s4[1];
    float v[8] = {a.x, a.y, a.z, a.w, b.x, b.y, b.z, b.w};
    union { ushort u[8]; uint4 q; } pk;
    #pragma unroll
    for (int j = 0; j < 8; ++j) {
        __hip_bfloat16 h = __float2bfloat16(v[j]);
        pk.u[j] = *reinterpret_cast<ushort*>(&h);
    }
    reinterpret_cast<uint4*>(dst)[t] = pk.q;
}

// ---------------- Phase A: MFMA GEMM  P_chunk[lk] = feats @ W[k0+lk] -------
// Wave = 16-row M-tile x 64 channels for one offset. Operand-swapped MFMA:
// E = (A*B)^T so lane l, reg r holds out[row = m16][chan = nt*16 + q*4 + r].
__global__ __launch_bounds__(256)
void gemm_mfma_kernel(const ushort* __restrict__ featsb,   // [NIN][C] bf16
                      const ushort* __restrict__ weightb,  // [KOFF][C][C] bf16
                      ushort* __restrict__ P,              // [kcnt][NIN][C] bf16
                      int k0)
{
    const int lk   = blockIdx.y;
    const int k    = k0 + lk;
    const int lane = threadIdx.x & 63;
    const int wave = threadIdx.x >> 6;
    const int m16  = lane & 15;
    const int q    = lane >> 4;        // 0..3

    // X fragments (first MFMA operand): X[nt][kc] slot j = W[kc*32+8q+j][nt*16+m16]
    const ushort* wb = weightb + (size_t)k * C * C;
    bf16x8 xf[4][2];
    #pragma unroll
    for (int nt = 0; nt < 4; ++nt)
        #pragma unroll
        for (int kc = 0; kc < 2; ++kc)
            #pragma unroll
            for (int j = 0; j < 8; ++j)
                xf[nt][kc][j] = (short)wb[(size_t)(kc * 32 + 8 * q + j) * C + nt * 16 + m16];

    ushort* Pk = P + (size_t)lk * NIN * C;
    const int tiles = NIN / 16;        // 6250 exactly

    for (int tile = blockIdx.x * 4 + wave; tile < tiles; tile += gridDim.x * 4) {
        const int mbase = tile * 16;
        const ushort* fr = featsb + (size_t)(mbase + m16) * C;
        bf16x8 y0 = *reinterpret_cast<const bf16x8*>(fr + 8 * q);        // k 0..31
        bf16x8 y1 = *reinterpret_cast<const bf16x8*>(fr + 32 + 8 * q);   // k 32..63

        f32x4 acc0 = {0,0,0,0}, acc1 = {0,0,0,0}, acc2 = {0,0,0,0}, acc3 = {0,0,0,0};
        acc0 = __builtin_amdgcn_mfma_f32_16x16x32_bf16(xf[0][0], y0, acc0, 0, 0, 0);
        acc1 = __builtin_amdgcn_mfma_f32_16x16x32_bf16(xf[1][0], y0, acc1, 0, 0, 0);
        acc2 = __builtin_amdgcn_mfma_f32_16x16x32_bf16(xf[2][0], y0, acc2, 0, 0, 0);
        acc3 = __builtin_amdgcn_mfma_f32_16x16x32_bf16(xf[3][0], y0, acc3, 0, 0, 0);
        acc0 = __builtin_amdgcn_mfma_f32_16x16x32_bf16(xf[0][1], y1, acc0, 0, 0, 0);
        acc1 = __builtin_amdgcn_mfma_f32_16x16x32_bf16(xf[1][1], y1, acc1, 0, 0, 0);
        acc2 = __builtin_amdgcn_mfma_f32_16x16x32_bf16(xf[2][1], y1, acc2, 0, 0, 0);
        acc3 = __builtin_amdgcn_mfma_f32_16x16x32_bf16(xf[3][1], y1, acc3, 0, 0, 0);

        ushort* prow = Pk + (size_t)(mbase + m16) * C;
        f32x4 accs[4] = {acc0, acc1, acc2, acc3};
        #pragma unroll
        for (int nt = 0; nt < 4; ++nt) {
            union { ushort u[4]; uint2 v; } pk;
            #pragma unroll
            for (int r = 0; r < 4; ++r) {
                __hip_bfloat16 h = __float2bfloat16(accs[nt][r]);
                pk.u[r] = *reinterpret_cast<ushort*>(&h);
            }
            *reinterpret_cast<uint2*>(prow + nt * 16 + q * 4) = pk.v;
        }
    }
}

// ---------------- Phase B: per-group CSR reverse maps ----------------------
__global__ __launch_bounds__(256)
void count_all_kernel(const int* __restrict__ out_idx, int* __restrict__ counts,
                      int kpg)
{
    int t = blockIdx.x * 256 + threadIdx.x;
    if (t < NPAIR) {
        int k = t / NIN;
        int g = k / kpg;
        atomicAdd(&counts[(size_t)g * NOUT + out_idx[t]], 1);
    }
}

__global__ __launch_bounds__(256)
void scan1_kernel(const int* __restrict__ counts, int* __restrict__ offsets,
                  int* __restrict__ blocksums)
{
    __shared__ int s[256];
    const int g   = blockIdx.y;
    const int t   = threadIdx.x;
    const int row = blockIdx.x * 256 + t;
    int v = (row < NOUT) ? counts[(size_t)g * NOUT + row] : 0;
    s[t] = v;
    __syncthreads();
    for (int off = 1; off < 256; off <<= 1) {
        int x = (t >= off) ? s[t - off] : 0;
        __syncthreads();
        s[t] += x;
        __syncthreads();
    }
    if (row < NOUT) offsets[(size_t)g * (NOUT + 1) + row] = s[t] - v;
    if (t == 255) blocksums[g * 1024 + blockIdx.x] = s[255];
}

__global__ __launch_bounds__(1024)
void scan2_kernel(int* __restrict__ blocksums, int* __restrict__ offsets)
{
    __shared__ int s[1024];
    const int g = blockIdx.x;
    const int t = threadIdx.x;
    int v = (t < NB_SCAN) ? blocksums[g * 1024 + t] : 0;
    s[t] = v;
    __syncthreads();
    for (int off = 1; off < 1024; off <<= 1) {
        int x = (t >= off) ? s[t - off] : 0;
        __syncthreads();
        s[t] += x;
        __syncthreads();
    }
    if (t < NB_SCAN) blocksums[g * 1024 + t] = s[t] - v;
    if (t == NB_SCAN - 1) offsets[(size_t)g * (NOUT + 1) + NOUT] = s[t];
}

__global__ __launch_bounds__(256)
void scan3_kernel(int* __restrict__ offsets, const int* __restrict__ blocksums,
                  int* __restrict__ cursor)
{
    const int g   = blockIdx.y;
    const int row = blockIdx.x * 256 + threadIdx.x;
    if (row < NOUT) {
        int o = offsets[(size_t)g * (NOUT + 1) + row] + blocksums[g * 1024 + blockIdx.x];
        offsets[(size_t)g * (NOUT + 1) + row] = o;
        cursor[(size_t)g * NOUT + row]        = o;
    }
}

__global__ __launch_bounds__(256)
void fill_all_kernel(const int* __restrict__ in_idx, const int* __restrict__ out_idx,
                     int* __restrict__ cursor, int* __restrict__ pairlist, int kpg)
{
    int t = blockIdx.x * 256 + threadIdx.x;
    if (t < NPAIR) {
        int k  = t / NIN;
        int g  = k / kpg;
        int oi = out_idx[t];
        int pos = atomicAdd(&cursor[(size_t)g * NOUT + oi], 1);
        pairlist[(size_t)g * kpg * NIN + pos] = (k - g * kpg) * NIN + in_idx[t];
    }
}

// ---------------- Phase C: gather-reduce (+accum) (+BN+ReLU last) ----------
// 16 threads per output row; each owns 4 channels (8B bf16x4 loads).
__global__ __launch_bounds__(256)
void gather_accum_kernel(const uint2* __restrict__ P2,      // P as bf16x4 chunks
                         const int* __restrict__ offsets,
                         const int* __restrict__ pairlist,
                         const float* __restrict__ gamma,
                         const float* __restrict__ beta,
                         const float* __restrict__ mean,
                         const float* __restrict__ var,
                         float* __restrict__ out,
                         int accumulate, int finalize)
{
    int tid = blockIdx.x * 256 + threadIdx.x;
    int row = tid >> 4;
    int cp  = tid & 15;
    if (row >= NOUT) return;

    const int beg = offsets[row];
    const int end = offsets[row + 1];

    float a0 = 0.f, a1 = 0.f, a2 = 0.f, a3 = 0.f;
    int j = beg;
    for (; j + 1 < end; j += 2) {                    // 2 loads in flight
        int p0 = pairlist[j];
        int p1 = pairlist[j + 1];
        uint2 u0 = P2[(size_t)p0 * 16 + cp];
        uint2 u1 = P2[(size_t)p1 * 16 + cp];
        a0 += __uint_as_float(u0.x << 16);
        a1 += __uint_as_float(u0.x & 0xffff0000u);
        a2 += __uint_as_float(u0.y << 16);
        a3 += __uint_as_float(u0.y & 0xffff0000u);
        a0 += __uint_as_float(u1.x << 16);
        a1 += __uint_as_float(u1.x & 0xffff0000u);
        a2 += __uint_as_float(u1.y << 16);
        a3 += __uint_as_float(u1.y & 0xffff0000u);
    }
    if (j < end) {
        uint2 u0 = P2[(size_t)pairlist[j] * 16 + cp];
        a0 += __uint_as_float(u0.x << 16);
        a1 += __uint_as_float(u0.x & 0xffff0000u);
        a2 += __uint_as_float(u0.y << 16);
        a3 += __uint_as_float(u0.y & 0xffff0000u);
    }

    float4* out4 = reinterpret_cast<float4*>(out);
    const size_t oidx = (size_t)row * 16 + cp;
    if (accumulate) {
        float4 v = out4[oidx];
        a0 += v.x; a1 += v.y; a2 += v.z; a3 += v.w;
    }
    if (finalize) {
        const int c0 = cp * 4;
        float acc[4] = {a0, a1, a2, a3};
        #pragma unroll
        for (int r = 0; r < 4; ++r) {
            const int c  = c0 + r;
            float s = gamma[c] * rsqrtf(var[c] + EPS);
            float y = fmaf(acc[r], s, beta[c] - mean[c] * s);
            acc[r] = y > 0.f ? y : 0.f;
        }
        a0 = acc[0]; a1 = acc[1]; a2 = acc[2]; a3 = acc[3];
    }
    out4[oidx] = make_float4(a0, a1, a2, a3);
}

// ---------------- Fallback (atomic path) -----------------------------------
__global__ __launch_bounds__(256)
void conv_scatter_kernel(const float* __restrict__ feats,
                         const float* __restrict__ weight,
                         const int*   __restrict__ in_idx,
                         const int*   __restrict__ out_idx,
                         float*       __restrict__ out)
{
    const int k    = blockIdx.y;
    const int lane = threadIdx.x & 63;
    const int wave = threadIdx.x >> 6;
    const int wavesInGrid = gridDim.x * 4;
    const int waveId      = blockIdx.x * 4 + wave;

    const float* wk = weight + (size_t)k * C * C + lane;
    float w[C];
    #pragma unroll
    for (int ci = 0; ci < C; ++ci) w[ci] = wk[(size_t)ci * C];

    const int* ii_k = in_idx  + (size_t)k * NIN;
    const int* oi_k = out_idx + (size_t)k * NIN;

    for (int r = waveId; r < NIN; r += wavesInGrid) {
        const int ii = ii_k[r];
        const int oi = oi_k[r];
        const float4* frow = reinterpret_cast<const float4*>(feats + (size_t)ii * C);
        float acc = 0.0f;
        #pragma unroll
        for (int j = 0; j < C / 4; ++j) {
            float4 f = frow[j];
            acc = fmaf(f.x, w[4 * j + 0], acc);
            acc = fmaf(f.y, w[4 * j + 1], acc);
            acc = fmaf(f.z, w[4 * j + 2], acc);
            acc = fmaf(f.w, w[4 * j + 3], acc);
        }
        atomicAdd(out + (size_t)oi * C + lane, acc);
    }
}

__global__ __launch_bounds__(256)
void bn_relu_kernel(float* __restrict__ out,
                    const float* __restrict__ gamma,
                    const float* __restrict__ beta,
                    const float* __restrict__ mean,
                    const float* __restrict__ var)
{
    const int total4 = NOUT * C / 4;
    int idx = blockIdx.x * blockDim.x + threadIdx.x;
    if (idx >= total4) return;
    const int c0 = (idx * 4) & (C - 1);
    float sc[4], sh[4];
    #pragma unroll
    for (int j = 0; j < 4; ++j) {
        const int c  = c0 + j;
        const float s = gamma[c] * rsqrtf(var[c] + EPS);
        sc[j] = s;
        sh[j] = beta[c] - mean[c] * s;
    }
    float4* p = reinterpret_cast<float4*>(out) + idx;
    float4 v = *p;
    v.x = fmaf(v.x, sc[0], sh[0]); v.x = v.x > 0.f ? v.x : 0.f;
    v.y = fmaf(v.y, sc[1], sh[1]); v.y = v.y > 0.f ? v.y : 0.f;
    v.z = fmaf(v.z, sc[2], sh[2]); v.z = v.z > 0.f ? v.z : 0.f;
    v.w = fmaf(v.w, sc[3], sh[3]); v.w = v.w > 0.f ? v.w : 0.f;
    *p = v;
}

// ---------------------------------------------------------------------------
extern "C" void kernel_launch(void* const* d_in, const int* in_sizes, int n_in,
                              void* d_out, int out_size, void* d_ws, size_t ws_size,
                              hipStream_t stream) {
    const float* feats   = (const float*)d_in[0];
    const float* weight  = (const float*)d_in[1];
    const int*   in_idx  = (const int*)  d_in[2];
    const int*   out_idx = (const int*)  d_in[3];
    const float* gamma   = (const float*)d_in[4];
    const float* beta    = (const float*)d_in[5];
    const float* rmean   = (const float*)d_in[6];
    const float* rvar    = (const float*)d_in[7];
    float* out = (float*)d_out;

    auto align = [](size_t x) { return (x + 255) & ~(size_t)255; };

    // Pick largest kpg <= 9 whose buffers fit ws_size (27 % kpg handled by grid).
    int kpg = 0, G = 0;
    size_t oCnt = 0, oOff = 0, oBlk = 0, oPair = 0, oP = 0, oFb = 0, oWb = 0;
    for (int t = 9; t >= 1; --t) {
        int g = (KOFF + t - 1) / t;
        size_t a = 0;
        size_t c_ = a; a += align((size_t)g * NOUT * 4);          // counts/cursor
        size_t f_ = a; a += align((size_t)g * (NOUT + 1) * 4);    // offsets
        size_t b_ = a; a += align((size_t)g * 1024 * 4);          // blocksums
        size_t p_ = a; a += align((size_t)NPAIR * 4);             // pairlist
        size_t fb = a; a += align((size_t)NIN * C * 2);           // feats bf16
        size_t wb = a; a += align((size_t)KOFF * C * C * 2);      // weight bf16
        size_t q_ = a; a += align((size_t)t * NIN * C * 2);       // P_chunk bf16
        if (a <= ws_size) {
            kpg = t; G = g; oCnt = c_; oOff = f_; oBlk = b_; oPair = p_;
            oFb = fb; oWb = wb; oP = q_;
            break;
        }
    }

    if (kpg == 0) {
        hipMemsetAsync(out, 0, (size_t)out_size * sizeof(float), stream);
        dim3 grid(512, KOFF);
        conv_scatter_kernel<<<grid, 256, 0, stream>>>(feats, weight, in_idx, out_idx, out);
        const int total4 = NOUT * C / 4;
        bn_relu_kernel<<<(total4 + 255) / 256, 256, 0, stream>>>(out, gamma, beta, rmean, rvar);
        return;
    }

    char* ws = (char*)d_ws;
    int* counts   = (int*)(ws + oCnt);    // doubles as cursor after scan
    int* offsets  = (int*)(ws + oOff);
    int* blksums  = (int*)(ws + oBlk);
    int* pairlist = (int*)(ws + oPair);
    ushort* featsb  = (ushort*)(ws + oFb);
    ushort* weightb = (ushort*)(ws + oWb);
    ushort* P       = (ushort*)(ws + oP);

    // --- bf16 conversions ---
    {
        int n8f = NIN * C / 8;
        cvt_bf16_kernel<<<(n8f + 255) / 256, 256, 0, stream>>>(feats, featsb, n8f);
        int n8w = KOFF * C * C / 8;
        cvt_bf16_kernel<<<(n8w + 255) / 256, 256, 0, stream>>>(weight, weightb, n8w);
    }

    // --- Build all G CSR reverse maps in one pass ---
    hipMemsetAsync(counts, 0, (size_t)G * NOUT * sizeof(int), stream);
    {
        int nb = (NPAIR + 255) / 256;
        count_all_kernel<<<nb, 256, 0, stream>>>(out_idx, counts, kpg);
        dim3 gs(NB_SCAN, G);
        scan1_kernel<<<gs, 256, 0, stream>>>(counts, offsets, blksums);
        scan2_kernel<<<G, 1024, 0, stream>>>(blksums, offsets);
        scan3_kernel<<<gs, 256, 0, stream>>>(offsets, blksums, counts /*cursor*/);
        fill_all_kernel<<<nb, 256, 0, stream>>>(in_idx, out_idx, counts, pairlist, kpg);
    }

    // --- Per-group: MFMA GEMM chunk, then gather-accumulate into out ---
    const int gatherBlocks = (NOUT * 16 + 255) / 256;
    for (int g = 0; g < G; ++g) {
        const int k0   = g * kpg;
        const int kcnt = (k0 + kpg <= KOFF) ? kpg : (KOFF - k0);

        dim3 grid(128, kcnt);
        gemm_mfma_kernel<<<grid, 256, 0, stream>>>(featsb, weightb, P, k0);

        gather_accum_kernel<<<gatherBlocks, 256, 0, stream>>>(
            (const uint2*)P,
            offsets + (size_t)g * (NOUT + 1),
            pairlist + (size_t)g * kpg * NIN,
            gamma, beta, rmean, rvar, out,
            /*accumulate=*/(g > 0), /*finalize=*/(g == G - 1));
    }
}

// Round 5
// 334.734 us; speedup vs baseline: 5.5739x; 1.7532x over previous
//
#include <hip/hip_runtime.h>
#include <hip/hip_bf16.h>
#include <stdint.h>

#define NIN    100000
#define NOUT   200000
#define KOFF   27
#define C      64
#define NPAIR  (KOFF * NIN)            // 2,700,000
#define EPS    1e-5f
#define NBUK   ((NOUT + 255) / 256)    // 782 buckets of 256 output rows
#define MAXGB  4704                    // >= G*NBUK for kpg >= 5 (G<=6)
#define IPB_F  12544                   // items per block, fill (49*256)
#define IPB_C  4096                    // items per block, count

typedef __attribute__((ext_vector_type(8))) short bf16x8;
typedef __attribute__((ext_vector_type(4))) float f32x4;

// ---------------- fp32 -> bf16 conversion (8 elems / thread) ---------------
__global__ __launch_bounds__(256)
void cvt_bf16_kernel(const float* __restrict__ src, ushort* __restrict__ dst, int n8)
{
    int t = blockIdx.x * 256 + threadIdx.x;
    if (t >= n8) return;
    const float4* s4 = reinterpret_cast<const float4*>(src) + (size_t)t * 2;
    float4 a = s4[0], b = s4[1];
    float v[8] = {a.x, a.y, a.z, a.w, b.x, b.y, b.z, b.w};
    union { ushort u[8]; uint4 q; } pk;
    #pragma unroll
    for (int j = 0; j < 8; ++j) {
        __hip_bfloat16 h = __float2bfloat16(v[j]);
        pk.u[j] = *reinterpret_cast<ushort*>(&h);
    }
    reinterpret_cast<uint4*>(dst)[t] = pk.q;
}

// ---------------- Phase A: MFMA GEMM  P_chunk[lk] = feats @ W[k0+lk] -------
// Wave = 16-row M-tile x 64 channels for one offset. Operand-swapped MFMA:
// lane l, reg r holds out[row = lane&15][chan = nt*16 + (lane>>4)*4 + r].
__global__ __launch_bounds__(256)
void gemm_mfma_kernel(const ushort* __restrict__ featsb,   // [NIN][C] bf16
                      const ushort* __restrict__ weightb,  // [KOFF][C][C] bf16
                      ushort* __restrict__ P,              // [kcnt][NIN][C] bf16
                      int k0)
{
    const int lk   = blockIdx.y;
    const int k    = k0 + lk;
    const int lane = threadIdx.x & 63;
    const int wave = threadIdx.x >> 6;
    const int m16  = lane & 15;
    const int q    = lane >> 4;        // 0..3

    const ushort* wb = weightb + (size_t)k * C * C;
    bf16x8 xf[4][2];
    #pragma unroll
    for (int nt = 0; nt < 4; ++nt)
        #pragma unroll
        for (int kc = 0; kc < 2; ++kc)
            #pragma unroll
            for (int j = 0; j < 8; ++j)
                xf[nt][kc][j] = (short)wb[(size_t)(kc * 32 + 8 * q + j) * C + nt * 16 + m16];

    ushort* Pk = P + (size_t)lk * NIN * C;
    const int tiles = NIN / 16;        // 6250 exactly

    for (int tile = blockIdx.x * 4 + wave; tile < tiles; tile += gridDim.x * 4) {
        const int mbase = tile * 16;
        const ushort* fr = featsb + (size_t)(mbase + m16) * C;
        bf16x8 y0 = *reinterpret_cast<const bf16x8*>(fr + 8 * q);
        bf16x8 y1 = *reinterpret_cast<const bf16x8*>(fr + 32 + 8 * q);

        f32x4 acc0 = {0,0,0,0}, acc1 = {0,0,0,0}, acc2 = {0,0,0,0}, acc3 = {0,0,0,0};
        acc0 = __builtin_amdgcn_mfma_f32_16x16x32_bf16(xf[0][0], y0, acc0, 0, 0, 0);
        acc1 = __builtin_amdgcn_mfma_f32_16x16x32_bf16(xf[1][0], y0, acc1, 0, 0, 0);
        acc2 = __builtin_amdgcn_mfma_f32_16x16x32_bf16(xf[2][0], y0, acc2, 0, 0, 0);
        acc3 = __builtin_amdgcn_mfma_f32_16x16x32_bf16(xf[3][0], y0, acc3, 0, 0, 0);
        acc0 = __builtin_amdgcn_mfma_f32_16x16x32_bf16(xf[0][1], y1, acc0, 0, 0, 0);
        acc1 = __builtin_amdgcn_mfma_f32_16x16x32_bf16(xf[1][1], y1, acc1, 0, 0, 0);
        acc2 = __builtin_amdgcn_mfma_f32_16x16x32_bf16(xf[2][1], y1, acc2, 0, 0, 0);
        acc3 = __builtin_amdgcn_mfma_f32_16x16x32_bf16(xf[3][1], y1, acc3, 0, 0, 0);

        ushort* prow = Pk + (size_t)(mbase + m16) * C;
        f32x4 accs[4] = {acc0, acc1, acc2, acc3};
        #pragma unroll
        for (int nt = 0; nt < 4; ++nt) {
            union { ushort u[4]; uint2 v; } pk;
            #pragma unroll
            for (int r = 0; r < 4; ++r) {
                __hip_bfloat16 h = __float2bfloat16(accs[nt][r]);
                pk.u[r] = *reinterpret_cast<ushort*>(&h);
            }
            *reinterpret_cast<uint2*>(prow + nt * 16 + q * 4) = pk.v;
        }
    }
}

// ---------------- Phase B: bucket binning ----------------------------------
// bucket (g,b) = pairs whose out_idx is in rows [b*256, b*256+256) for group g.
// Payload: bits[0,17)=ii  bits[17,21)=lk (group-local k)  bits[21,29)=oi&255.

__global__ __launch_bounds__(256)
void bin_count_kernel(const int* __restrict__ out_idx, int* __restrict__ bcnt,
                      int kpg, int GB)
{
    __shared__ int hist[MAXGB];
    for (int i = threadIdx.x; i < GB; i += 256) hist[i] = 0;
    __syncthreads();
    const int t0 = blockIdx.x * IPB_C;
    #pragma unroll 4
    for (int j = 0; j < IPB_C / 256; ++j) {
        int t = t0 + j * 256 + threadIdx.x;
        if (t < NPAIR) {
            int g  = (t / NIN) / kpg;
            int oi = out_idx[t];
            atomicAdd(&hist[g * NBUK + (oi >> 8)], 1);
        }
    }
    __syncthreads();
    for (int i = threadIdx.x; i < GB; i += 256) {
        int c = hist[i];
        if (c) atomicAdd(&bcnt[i], c);
    }
}

// exclusive scan of bcnt[GB] -> boff[GB+1]; bcur := boff.  One block.
__global__ __launch_bounds__(1024)
void bucket_scan_kernel(const int* __restrict__ bcnt, int* __restrict__ boff,
                        int* __restrict__ bcur, int GB)
{
    __shared__ int s[1024];
    const int t   = threadIdx.x;
    const int per = (GB + 1023) / 1024;      // <= 5
    int local[8];
    int sum = 0;
    for (int j = 0; j < per; ++j) {
        int idx = t * per + j;
        int v = (idx < GB) ? bcnt[idx] : 0;
        local[j] = sum;
        sum += v;
    }
    s[t] = sum;
    __syncthreads();
    for (int off = 1; off < 1024; off <<= 1) {
        int x = (t >= off) ? s[t - off] : 0;
        __syncthreads();
        s[t] += x;
        __syncthreads();
    }
    int tbase = (t > 0) ? s[t - 1] : 0;
    for (int j = 0; j < per; ++j) {
        int idx = t * per + j;
        if (idx < GB) {
            int o = tbase + local[j];
            boff[idx] = o;
            bcur[idx] = o;
        }
    }
    if (t == 1023) boff[GB] = s[1023];
}

// Per-block: LDS hist -> reserve global ranges -> write payloads in runs.
__global__ __launch_bounds__(256)
void bin_fill_kernel(const int* __restrict__ in_idx, const int* __restrict__ out_idx,
                     int* __restrict__ bcur, uint32_t* __restrict__ binned,
                     int kpg, int GB)
{
    __shared__ int hist[MAXGB];
    __shared__ int base[MAXGB];
    for (int i = threadIdx.x; i < GB; i += 256) hist[i] = 0;
    __syncthreads();
    const int t0 = blockIdx.x * IPB_F;
    for (int j = 0; j < IPB_F / 256; ++j) {
        int t = t0 + j * 256 + threadIdx.x;
        if (t < NPAIR) {
            int g  = (t / NIN) / kpg;
            int oi = out_idx[t];
            atomicAdd(&hist[g * NBUK + (oi >> 8)], 1);
        }
    }
    __syncthreads();
    for (int i = threadIdx.x; i < GB; i += 256) {
        int c = hist[i];
        base[i] = c ? atomicAdd(&bcur[i], c) : 0;
    }
    __syncthreads();
    for (int j = 0; j < IPB_F / 256; ++j) {
        int t = t0 + j * 256 + threadIdx.x;
        if (t < NPAIR) {
            int k   = t / NIN;
            int g   = k / kpg;
            int oi  = out_idx[t];
            int ii  = in_idx[t];
            int bkt = g * NBUK + (oi >> 8);
            int p   = atomicSub(&hist[bkt], 1) - 1;
            uint32_t payload = ((uint32_t)(oi & 255) << 21)
                             | ((uint32_t)(k - g * kpg) << 17)
                             | (uint32_t)ii;
            binned[base[bkt] + p] = payload;
        }
    }
}

// ---------------- Phase C: per-bucket LDS sort + gather + BN/ReLU ----------
// Block = one bucket (256 output rows). Counting-sort payloads by row in LDS,
// then 16 threads per row reduce P rows (128B coalesced per item).
__global__ __launch_bounds__(256)
void gather_bucket_kernel(const uint2* __restrict__ P2,
                          const uint32_t* __restrict__ binned,
                          const int* __restrict__ boff, int gbase,
                          const float* __restrict__ gamma,
                          const float* __restrict__ beta,
                          const float* __restrict__ mean,
                          const float* __restrict__ var,
                          float* __restrict__ out,
                          int accumulate, int finalize)
{
    __shared__ uint32_t sIt[4096];
    __shared__ int sCnt[256];
    __shared__ int sOff[257];
    __shared__ int sCur[256];

    const int b = blockIdx.x;
    const int t = threadIdx.x;
    const int beg = boff[gbase + b];
    int n = boff[gbase + b + 1] - beg;
    if (n > 4096) n = 4096;            // statistically unreachable

    sCnt[t] = 0;
    __syncthreads();
    for (int i = t; i < n; i += 256)
        atomicAdd(&sCnt[binned[beg + i] >> 21], 1);
    __syncthreads();
    // inclusive scan of sCnt
    int v = sCnt[t];
    int run = v;
    // Hillis-Steele using sOff[1..] as scratch
    sOff[t + 1] = run;
    __syncthreads();
    for (int off = 1; off < 256; off <<= 1) {
        int x = (t >= off) ? sOff[t + 1 - off] : 0;
        __syncthreads();
        sOff[t + 1] += x;
        __syncthreads();
    }
    if (t == 0) sOff[0] = 0;
    __syncthreads();
    sCur[t] = sOff[t + 1] - v;         // exclusive start per row
    __syncthreads();
    for (int i = t; i < n; i += 256) {
        uint32_t pl = binned[beg + i];
        int slot = atomicAdd(&sCur[pl >> 21], 1);
        sIt[slot] = pl;
    }
    __syncthreads();

    const int cp = t & 15;
    const int c0 = cp * 4;
    float sc[4], sh[4];
    if (finalize) {
        #pragma unroll
        for (int r = 0; r < 4; ++r) {
            const int c = c0 + r;
            float s = gamma[c] * rsqrtf(var[c] + EPS);
            sc[r] = s;
            sh[r] = beta[c] - mean[c] * s;
        }
    }

    float4* out4 = reinterpret_cast<float4*>(out);
    #pragma unroll 1
    for (int it = 0; it < 16; ++it) {
        const int rl  = (t >> 4) + it * 16;
        const int row = b * 256 + rl;
        if (row >= NOUT) continue;
        int j  = sOff[rl];
        const int je = sOff[rl + 1];

        float a0 = 0.f, a1 = 0.f, a2 = 0.f, a3 = 0.f;
        for (; j + 1 < je; j += 2) {
            uint32_t p0 = sIt[j], p1 = sIt[j + 1];
            uint2 u0 = P2[((size_t)((p0 >> 17) & 15) * NIN + (p0 & 0x1FFFF)) * 16 + cp];
            uint2 u1 = P2[((size_t)((p1 >> 17) & 15) * NIN + (p1 & 0x1FFFF)) * 16 + cp];
            a0 += __uint_as_float(u0.x << 16);
            a1 += __uint_as_float(u0.x & 0xffff0000u);
            a2 += __uint_as_float(u0.y << 16);
            a3 += __uint_as_float(u0.y & 0xffff0000u);
            a0 += __uint_as_float(u1.x << 16);
            a1 += __uint_as_float(u1.x & 0xffff0000u);
            a2 += __uint_as_float(u1.y << 16);
            a3 += __uint_as_float(u1.y & 0xffff0000u);
        }
        if (j < je) {
            uint32_t p0 = sIt[j];
            uint2 u0 = P2[((size_t)((p0 >> 17) & 15) * NIN + (p0 & 0x1FFFF)) * 16 + cp];
            a0 += __uint_as_float(u0.x << 16);
            a1 += __uint_as_float(u0.x & 0xffff0000u);
            a2 += __uint_as_float(u0.y << 16);
            a3 += __uint_as_float(u0.y & 0xffff0000u);
        }

        const size_t oidx = (size_t)row * 16 + cp;
        if (accumulate) {
            float4 pv = out4[oidx];
            a0 += pv.x; a1 += pv.y; a2 += pv.z; a3 += pv.w;
        }
        if (finalize) {
            a0 = fmaf(a0, sc[0], sh[0]); a0 = a0 > 0.f ? a0 : 0.f;
            a1 = fmaf(a1, sc[1], sh[1]); a1 = a1 > 0.f ? a1 : 0.f;
            a2 = fmaf(a2, sc[2], sh[2]); a2 = a2 > 0.f ? a2 : 0.f;
            a3 = fmaf(a3, sc[3], sh[3]); a3 = a3 > 0.f ? a3 : 0.f;
        }
        out4[oidx] = make_float4(a0, a1, a2, a3);
    }
}

// ---------------- Fallback (atomic path, tiny ws) --------------------------
__global__ __launch_bounds__(256)
void conv_scatter_kernel(const float* __restrict__ feats,
                         const float* __restrict__ weight,
                         const int*   __restrict__ in_idx,
                         const int*   __restrict__ out_idx,
                         float*       __restrict__ out)
{
    const int k    = blockIdx.y;
    const int lane = threadIdx.x & 63;
    const int wave = threadIdx.x >> 6;
    const int wavesInGrid = gridDim.x * 4;
    const int waveId      = blockIdx.x * 4 + wave;

    const float* wk = weight + (size_t)k * C * C + lane;
    float w[C];
    #pragma unroll
    for (int ci = 0; ci < C; ++ci) w[ci] = wk[(size_t)ci * C];

    const int* ii_k = in_idx  + (size_t)k * NIN;
    const int* oi_k = out_idx + (size_t)k * NIN;

    for (int r = waveId; r < NIN; r += wavesInGrid) {
        const int ii = ii_k[r];
        const int oi = oi_k[r];
        const float4* frow = reinterpret_cast<const float4*>(feats + (size_t)ii * C);
        float acc = 0.0f;
        #pragma unroll
        for (int j = 0; j < C / 4; ++j) {
            float4 f = frow[j];
            acc = fmaf(f.x, w[4 * j + 0], acc);
            acc = fmaf(f.y, w[4 * j + 1], acc);
            acc = fmaf(f.z, w[4 * j + 2], acc);
            acc = fmaf(f.w, w[4 * j + 3], acc);
        }
        atomicAdd(out + (size_t)oi * C + lane, acc);
    }
}

__global__ __launch_bounds__(256)
void bn_relu_kernel(float* __restrict__ out,
                    const float* __restrict__ gamma,
                    const float* __restrict__ beta,
                    const float* __restrict__ mean,
                    const float* __restrict__ var)
{
    const int total4 = NOUT * C / 4;
    int idx = blockIdx.x * blockDim.x + threadIdx.x;
    if (idx >= total4) return;
    const int c0 = (idx * 4) & (C - 1);
    float sc[4], sh[4];
    #pragma unroll
    for (int j = 0; j < 4; ++j) {
        const int c  = c0 + j;
        const float s = gamma[c] * rsqrtf(var[c] + EPS);
        sc[j] = s;
        sh[j] = beta[c] - mean[c] * s;
    }
    float4* p = reinterpret_cast<float4*>(out) + idx;
    float4 v = *p;
    v.x = fmaf(v.x, sc[0], sh[0]); v.x = v.x > 0.f ? v.x : 0.f;
    v.y = fmaf(v.y, sc[1], sh[1]); v.y = v.y > 0.f ? v.y : 0.f;
    v.z = fmaf(v.z, sc[2], sh[2]); v.z = v.z > 0.f ? v.z : 0.f;
    v.w = fmaf(v.w, sc[3], sh[3]); v.w = v.w > 0.f ? v.w : 0.f;
    *p = v;
}

// ---------------------------------------------------------------------------
extern "C" void kernel_launch(void* const* d_in, const int* in_sizes, int n_in,
                              void* d_out, int out_size, void* d_ws, size_t ws_size,
                              hipStream_t stream) {
    const float* feats   = (const float*)d_in[0];
    const float* weight  = (const float*)d_in[1];
    const int*   in_idx  = (const int*)  d_in[2];
    const int*   out_idx = (const int*)  d_in[3];
    const float* gamma   = (const float*)d_in[4];
    const float* beta    = (const float*)d_in[5];
    const float* rmean   = (const float*)d_in[6];
    const float* rvar    = (const float*)d_in[7];
    float* out = (float*)d_out;

    auto align = [](size_t x) { return (x + 255) & ~(size_t)255; };

    // Pick largest kpg in [5,16] whose buffers fit (lk payload field = 4 bits).
    int kpg = 0, G = 0;
    size_t oBin = 0, oBcnt = 0, oBoff = 0, oBcur = 0, oFb = 0, oWb = 0, oP = 0;
    for (int t = 16; t >= 5; --t) {
        int g  = (KOFF + t - 1) / t;
        int gb = g * NBUK;
        size_t a = 0;
        size_t bi = a; a += align((size_t)NPAIR * 4);             // binned payloads
        size_t bc = a; a += align((size_t)gb * 4);                // bcnt
        size_t bo = a; a += align((size_t)(gb + 1) * 4);          // boff
        size_t bu = a; a += align((size_t)gb * 4);                // bcur
        size_t fb = a; a += align((size_t)NIN * C * 2);           // feats bf16
        size_t wb = a; a += align((size_t)KOFF * C * C * 2);      // weight bf16
        size_t q_ = a; a += align((size_t)t * NIN * C * 2);       // P_chunk bf16
        if (a <= ws_size) {
            kpg = t; G = g;
            oBin = bi; oBcnt = bc; oBoff = bo; oBcur = bu; oFb = fb; oWb = wb; oP = q_;
            break;
        }
    }

    if (kpg == 0) {
        hipMemsetAsync(out, 0, (size_t)out_size * sizeof(float), stream);
        dim3 grid(512, KOFF);
        conv_scatter_kernel<<<grid, 256, 0, stream>>>(feats, weight, in_idx, out_idx, out);
        const int total4 = NOUT * C / 4;
        bn_relu_kernel<<<(total4 + 255) / 256, 256, 0, stream>>>(out, gamma, beta, rmean, rvar);
        return;
    }

    const int GB = G * NBUK;
    char* ws = (char*)d_ws;
    uint32_t* binned = (uint32_t*)(ws + oBin);
    int* bcnt = (int*)(ws + oBcnt);
    int* boff = (int*)(ws + oBoff);
    int* bcur = (int*)(ws + oBcur);
    ushort* featsb  = (ushort*)(ws + oFb);
    ushort* weightb = (ushort*)(ws + oWb);
    ushort* P       = (ushort*)(ws + oP);

    // --- bf16 conversions ---
    {
        int n8f = NIN * C / 8;
        cvt_bf16_kernel<<<(n8f + 255) / 256, 256, 0, stream>>>(feats, featsb, n8f);
        int n8w = KOFF * C * C / 8;
        cvt_bf16_kernel<<<(n8w + 255) / 256, 256, 0, stream>>>(weight, weightb, n8w);
    }

    // --- Bucket binning ---
    hipMemsetAsync(bcnt, 0, (size_t)GB * sizeof(int), stream);
    {
        int nbC = (NPAIR + IPB_C - 1) / IPB_C;
        bin_count_kernel<<<nbC, 256, 0, stream>>>(out_idx, bcnt, kpg, GB);
        bucket_scan_kernel<<<1, 1024, 0, stream>>>(bcnt, boff, bcur, GB);
        int nbF = (NPAIR + IPB_F - 1) / IPB_F;
        bin_fill_kernel<<<nbF, 256, 0, stream>>>(in_idx, out_idx, bcur, binned, kpg, GB);
    }

    // --- Per-group: MFMA GEMM chunk, then bucket gather into out ---
    for (int g = 0; g < G; ++g) {
        const int k0   = g * kpg;
        const int kcnt = (k0 + kpg <= KOFF) ? kpg : (KOFF - k0);

        dim3 grid(128, kcnt);
        gemm_mfma_kernel<<<grid, 256, 0, stream>>>(featsb, weightb, P, k0);

        gather_bucket_kernel<<<NBUK, 256, 0, stream>>>(
            (const uint2*)P, binned, boff, g * NBUK,
            gamma, beta, rmean, rvar, out,
            /*accumulate=*/(g > 0), /*finalize=*/(g == G - 1));
    }
}

// Round 6
// 306.671 us; speedup vs baseline: 6.0839x; 1.0915x over previous
//
#include <hip/hip_runtime.h>
#include <hip/hip_bf16.h>
#include <stdint.h>

#define NIN    100000
#define NOUT   200000
#define KOFF   27
#define C      64
#define NPAIR  (KOFF * NIN)            // 2,700,000
#define EPS    1e-5f
#define NBUK   ((NOUT + 255) / 256)    // 782 buckets of 256 output rows
#define MAXGB  4704                    // >= G*NBUK for kpg >= 5 (G<=6)
#define IPB_F  12544                   // items per block, fill (49*256)
#define IPB_C  4096                    // items per block, count
#define RPB    128                     // rows per gather sub-block
#define SIT    3072                    // sorted-item capacity per sub-block

typedef __attribute__((ext_vector_type(8))) short bf16x8;
typedef __attribute__((ext_vector_type(4))) float f32x4;

// ---------------- fp32 -> bf16 conversion (8 elems / thread) ---------------
__global__ __launch_bounds__(256)
void cvt_bf16_kernel(const float* __restrict__ src, ushort* __restrict__ dst, int n8)
{
    int t = blockIdx.x * 256 + threadIdx.x;
    if (t >= n8) return;
    const float4* s4 = reinterpret_cast<const float4*>(src) + (size_t)t * 2;
    float4 a = s4[0], b = s4[1];
    float v[8] = {a.x, a.y, a.z, a.w, b.x, b.y, b.z, b.w};
    union { ushort u[8]; uint4 q; } pk;
    #pragma unroll
    for (int j = 0; j < 8; ++j) {
        __hip_bfloat16 h = __float2bfloat16(v[j]);
        pk.u[j] = *reinterpret_cast<ushort*>(&h);
    }
    reinterpret_cast<uint4*>(dst)[t] = pk.q;
}

// ---------------- Phase A: MFMA GEMM  P_chunk[lk] = feats @ W[k0+lk] -------
// Wave = 16-row M-tile x 64 channels for one offset. Operand-swapped MFMA:
// lane l, reg r holds out[row = lane&15][chan = nt*16 + (lane>>4)*4 + r].
__global__ __launch_bounds__(256)
void gemm_mfma_kernel(const ushort* __restrict__ featsb,   // [NIN][C] bf16
                      const ushort* __restrict__ weightb,  // [KOFF][C][C] bf16
                      ushort* __restrict__ P,              // [kcnt][NIN][C] bf16
                      int k0)
{
    const int lk   = blockIdx.y;
    const int k    = k0 + lk;
    const int lane = threadIdx.x & 63;
    const int wave = threadIdx.x >> 6;
    const int m16  = lane & 15;
    const int q    = lane >> 4;        // 0..3

    const ushort* wb = weightb + (size_t)k * C * C;
    bf16x8 xf[4][2];
    #pragma unroll
    for (int nt = 0; nt < 4; ++nt)
        #pragma unroll
        for (int kc = 0; kc < 2; ++kc)
            #pragma unroll
            for (int j = 0; j < 8; ++j)
                xf[nt][kc][j] = (short)wb[(size_t)(kc * 32 + 8 * q + j) * C + nt * 16 + m16];

    ushort* Pk = P + (size_t)lk * NIN * C;
    const int tiles = NIN / 16;        // 6250 exactly

    for (int tile = blockIdx.x * 4 + wave; tile < tiles; tile += gridDim.x * 4) {
        const int mbase = tile * 16;
        const ushort* fr = featsb + (size_t)(mbase + m16) * C;
        bf16x8 y0 = *reinterpret_cast<const bf16x8*>(fr + 8 * q);
        bf16x8 y1 = *reinterpret_cast<const bf16x8*>(fr + 32 + 8 * q);

        f32x4 acc0 = {0,0,0,0}, acc1 = {0,0,0,0}, acc2 = {0,0,0,0}, acc3 = {0,0,0,0};
        acc0 = __builtin_amdgcn_mfma_f32_16x16x32_bf16(xf[0][0], y0, acc0, 0, 0, 0);
        acc1 = __builtin_amdgcn_mfma_f32_16x16x32_bf16(xf[1][0], y0, acc1, 0, 0, 0);
        acc2 = __builtin_amdgcn_mfma_f32_16x16x32_bf16(xf[2][0], y0, acc2, 0, 0, 0);
        acc3 = __builtin_amdgcn_mfma_f32_16x16x32_bf16(xf[3][0], y0, acc3, 0, 0, 0);
        acc0 = __builtin_amdgcn_mfma_f32_16x16x32_bf16(xf[0][1], y1, acc0, 0, 0, 0);
        acc1 = __builtin_amdgcn_mfma_f32_16x16x32_bf16(xf[1][1], y1, acc1, 0, 0, 0);
        acc2 = __builtin_amdgcn_mfma_f32_16x16x32_bf16(xf[2][1], y1, acc2, 0, 0, 0);
        acc3 = __builtin_amdgcn_mfma_f32_16x16x32_bf16(xf[3][1], y1, acc3, 0, 0, 0);

        ushort* prow = Pk + (size_t)(mbase + m16) * C;
        f32x4 accs[4] = {acc0, acc1, acc2, acc3};
        #pragma unroll
        for (int nt = 0; nt < 4; ++nt) {
            union { ushort u[4]; uint2 v; } pk;
            #pragma unroll
            for (int r = 0; r < 4; ++r) {
                __hip_bfloat16 h = __float2bfloat16(accs[nt][r]);
                pk.u[r] = *reinterpret_cast<ushort*>(&h);
            }
            *reinterpret_cast<uint2*>(prow + nt * 16 + q * 4) = pk.v;
        }
    }
}

// ---------------- Phase B: bucket binning ----------------------------------
// bucket (g,b) = pairs whose out_idx is in rows [b*256, b*256+256) for group g.
// Payload: bits[0,17)=ii  bits[17,21)=lk (group-local k)  bits[21,29)=oi&255.

__global__ __launch_bounds__(256)
void bin_count_kernel(const int* __restrict__ out_idx, int* __restrict__ bcnt,
                      int kpg, int GB)
{
    __shared__ int hist[MAXGB];
    for (int i = threadIdx.x; i < GB; i += 256) hist[i] = 0;
    __syncthreads();
    const int t0 = blockIdx.x * IPB_C;
    #pragma unroll 4
    for (int j = 0; j < IPB_C / 256; ++j) {
        int t = t0 + j * 256 + threadIdx.x;
        if (t < NPAIR) {
            int g  = (t / NIN) / kpg;
            int oi = out_idx[t];
            atomicAdd(&hist[g * NBUK + (oi >> 8)], 1);
        }
    }
    __syncthreads();
    for (int i = threadIdx.x; i < GB; i += 256) {
        int c = hist[i];
        if (c) atomicAdd(&bcnt[i], c);
    }
}

// exclusive scan of bcnt[GB] -> boff[GB+1]; bcur := boff.  One block.
__global__ __launch_bounds__(1024)
void bucket_scan_kernel(const int* __restrict__ bcnt, int* __restrict__ boff,
                        int* __restrict__ bcur, int GB)
{
    __shared__ int s[1024];
    const int t   = threadIdx.x;
    const int per = (GB + 1023) / 1024;      // <= 5
    int local[8];
    int sum = 0;
    for (int j = 0; j < per; ++j) {
        int idx = t * per + j;
        int v = (idx < GB) ? bcnt[idx] : 0;
        local[j] = sum;
        sum += v;
    }
    s[t] = sum;
    __syncthreads();
    for (int off = 1; off < 1024; off <<= 1) {
        int x = (t >= off) ? s[t - off] : 0;
        __syncthreads();
        s[t] += x;
        __syncthreads();
    }
    int tbase = (t > 0) ? s[t - 1] : 0;
    for (int j = 0; j < per; ++j) {
        int idx = t * per + j;
        if (idx < GB) {
            int o = tbase + local[j];
            boff[idx] = o;
            bcur[idx] = o;
        }
    }
    if (t == 1023) boff[GB] = s[1023];
}

// Per-block: LDS hist -> reserve global ranges -> write payloads in runs.
__global__ __launch_bounds__(256)
void bin_fill_kernel(const int* __restrict__ in_idx, const int* __restrict__ out_idx,
                     int* __restrict__ bcur, uint32_t* __restrict__ binned,
                     int kpg, int GB)
{
    __shared__ int hist[MAXGB];
    __shared__ int base[MAXGB];
    for (int i = threadIdx.x; i < GB; i += 256) hist[i] = 0;
    __syncthreads();
    const int t0 = blockIdx.x * IPB_F;
    for (int j = 0; j < IPB_F / 256; ++j) {
        int t = t0 + j * 256 + threadIdx.x;
        if (t < NPAIR) {
            int g  = (t / NIN) / kpg;
            int oi = out_idx[t];
            atomicAdd(&hist[g * NBUK + (oi >> 8)], 1);
        }
    }
    __syncthreads();
    for (int i = threadIdx.x; i < GB; i += 256) {
        int c = hist[i];
        base[i] = c ? atomicAdd(&bcur[i], c) : 0;
    }
    __syncthreads();
    for (int j = 0; j < IPB_F / 256; ++j) {
        int t = t0 + j * 256 + threadIdx.x;
        if (t < NPAIR) {
            int k   = t / NIN;
            int g   = k / kpg;
            int oi  = out_idx[t];
            int ii  = in_idx[t];
            int bkt = g * NBUK + (oi >> 8);
            int p   = atomicSub(&hist[bkt], 1) - 1;
            uint32_t payload = ((uint32_t)(oi & 255) << 21)
                             | ((uint32_t)(k - g * kpg) << 17)
                             | (uint32_t)ii;
            binned[base[bkt] + p] = payload;
        }
    }
}

// ---------------- Phase C: per-half-bucket LDS sort + gather + BN/ReLU -----
// Block = (bucket b, half sub): 128 output rows. Counting-sort the bucket's
// payloads that land in this half, then 16 threads/row reduce P rows with
// 4-deep load ILP.
__global__ __launch_bounds__(256)
void gather_bucket_kernel(const uint2* __restrict__ P2,
                          const uint32_t* __restrict__ binned,
                          const int* __restrict__ boff, int gbase,
                          const float* __restrict__ gamma,
                          const float* __restrict__ beta,
                          const float* __restrict__ mean,
                          const float* __restrict__ var,
                          float* __restrict__ out,
                          int accumulate, int finalize)
{
    __shared__ uint32_t sIt[SIT];
    __shared__ int sCnt[RPB];
    __shared__ int sOff[RPB + 1];
    __shared__ int sCur[RPB];

    const int b   = blockIdx.x;
    const int sub = blockIdx.y;                  // 0/1 -> rows [sub*128, +128)
    const int t   = threadIdx.x;
    const int beg = boff[gbase + b];
    const int n   = boff[gbase + b + 1] - beg;
    const int rlo = sub * RPB;

    if (t < RPB) sCnt[t] = 0;
    __syncthreads();
    for (int i = t; i < n; i += 256) {
        int rl = (int)(binned[beg + i] >> 21) - rlo;
        if ((unsigned)rl < (unsigned)RPB) atomicAdd(&sCnt[rl], 1);
    }
    __syncthreads();
    // inclusive scan over RPB entries (first 128 threads)
    if (t < RPB) sOff[t + 1] = sCnt[t];
    __syncthreads();
    for (int off = 1; off < RPB; off <<= 1) {
        int x = 0;
        if (t < RPB && t >= off) x = sOff[t + 1 - off];
        __syncthreads();
        if (t < RPB) sOff[t + 1] += x;
        __syncthreads();
    }
    if (t == 0) sOff[0] = 0;
    __syncthreads();
    if (t < RPB) sCur[t] = sOff[t + 1] - sCnt[t];
    __syncthreads();
    for (int i = t; i < n; i += 256) {
        uint32_t pl = binned[beg + i];
        int rl = (int)(pl >> 21) - rlo;
        if ((unsigned)rl < (unsigned)RPB) {
            int slot = atomicAdd(&sCur[rl], 1);
            if (slot < SIT) sIt[slot] = pl;
        }
    }
    __syncthreads();

    const int cp = t & 15;
    const int c0 = cp * 4;
    float sc[4], sh[4];
    if (finalize) {
        #pragma unroll
        for (int r = 0; r < 4; ++r) {
            const int c = c0 + r;
            float s = gamma[c] * rsqrtf(var[c] + EPS);
            sc[r] = s;
            sh[r] = beta[c] - mean[c] * s;
        }
    }

    float4* out4 = reinterpret_cast<float4*>(out);
    #pragma unroll 1
    for (int it = 0; it < RPB / 16; ++it) {
        const int rl  = (t >> 4) + it * 16;
        const int row = b * 256 + rlo + rl;
        if (row >= NOUT) continue;
        int j  = sOff[rl];
        const int je = sOff[rl + 1];

        float a0 = 0.f, a1 = 0.f, a2 = 0.f, a3 = 0.f;
        for (; j + 3 < je; j += 4) {              // 4 loads in flight
            uint32_t p0 = sIt[j],     p1 = sIt[j + 1];
            uint32_t p2 = sIt[j + 2], p3 = sIt[j + 3];
            uint2 u0 = P2[((size_t)((p0 >> 17) & 15) * NIN + (p0 & 0x1FFFF)) * 16 + cp];
            uint2 u1 = P2[((size_t)((p1 >> 17) & 15) * NIN + (p1 & 0x1FFFF)) * 16 + cp];
            uint2 u2 = P2[((size_t)((p2 >> 17) & 15) * NIN + (p2 & 0x1FFFF)) * 16 + cp];
            uint2 u3 = P2[((size_t)((p3 >> 17) & 15) * NIN + (p3 & 0x1FFFF)) * 16 + cp];
            a0 += __uint_as_float(u0.x << 16);
            a1 += __uint_as_float(u0.x & 0xffff0000u);
            a2 += __uint_as_float(u0.y << 16);
            a3 += __uint_as_float(u0.y & 0xffff0000u);
            a0 += __uint_as_float(u1.x << 16);
            a1 += __uint_as_float(u1.x & 0xffff0000u);
            a2 += __uint_as_float(u1.y << 16);
            a3 += __uint_as_float(u1.y & 0xffff0000u);
            a0 += __uint_as_float(u2.x << 16);
            a1 += __uint_as_float(u2.x & 0xffff0000u);
            a2 += __uint_as_float(u2.y << 16);
            a3 += __uint_as_float(u2.y & 0xffff0000u);
            a0 += __uint_as_float(u3.x << 16);
            a1 += __uint_as_float(u3.x & 0xffff0000u);
            a2 += __uint_as_float(u3.y << 16);
            a3 += __uint_as_float(u3.y & 0xffff0000u);
        }
        for (; j < je; ++j) {
            uint32_t p0 = sIt[j];
            uint2 u0 = P2[((size_t)((p0 >> 17) & 15) * NIN + (p0 & 0x1FFFF)) * 16 + cp];
            a0 += __uint_as_float(u0.x << 16);
            a1 += __uint_as_float(u0.x & 0xffff0000u);
            a2 += __uint_as_float(u0.y << 16);
            a3 += __uint_as_float(u0.y & 0xffff0000u);
        }

        const size_t oidx = (size_t)row * 16 + cp;
        if (accumulate) {
            float4 pv = out4[oidx];
            a0 += pv.x; a1 += pv.y; a2 += pv.z; a3 += pv.w;
        }
        if (finalize) {
            a0 = fmaf(a0, sc[0], sh[0]); a0 = a0 > 0.f ? a0 : 0.f;
            a1 = fmaf(a1, sc[1], sh[1]); a1 = a1 > 0.f ? a1 : 0.f;
            a2 = fmaf(a2, sc[2], sh[2]); a2 = a2 > 0.f ? a2 : 0.f;
            a3 = fmaf(a3, sc[3], sh[3]); a3 = a3 > 0.f ? a3 : 0.f;
        }
        out4[oidx] = make_float4(a0, a1, a2, a3);
    }
}

// ---------------- Fallback (atomic path, tiny ws) --------------------------
__global__ __launch_bounds__(256)
void conv_scatter_kernel(const float* __restrict__ feats,
                         const float* __restrict__ weight,
                         const int*   __restrict__ in_idx,
                         const int*   __restrict__ out_idx,
                         float*       __restrict__ out)
{
    const int k    = blockIdx.y;
    const int lane = threadIdx.x & 63;
    const int wave = threadIdx.x >> 6;
    const int wavesInGrid = gridDim.x * 4;
    const int waveId      = blockIdx.x * 4 + wave;

    const float* wk = weight + (size_t)k * C * C + lane;
    float w[C];
    #pragma unroll
    for (int ci = 0; ci < C; ++ci) w[ci] = wk[(size_t)ci * C];

    const int* ii_k = in_idx  + (size_t)k * NIN;
    const int* oi_k = out_idx + (size_t)k * NIN;

    for (int r = waveId; r < NIN; r += wavesInGrid) {
        const int ii = ii_k[r];
        const int oi = oi_k[r];
        const float4* frow = reinterpret_cast<const float4*>(feats + (size_t)ii * C);
        float acc = 0.0f;
        #pragma unroll
        for (int j = 0; j < C / 4; ++j) {
            float4 f = frow[j];
            acc = fmaf(f.x, w[4 * j + 0], acc);
            acc = fmaf(f.y, w[4 * j + 1], acc);
            acc = fmaf(f.z, w[4 * j + 2], acc);
            acc = fmaf(f.w, w[4 * j + 3], acc);
        }
        atomicAdd(out + (size_t)oi * C + lane, acc);
    }
}

__global__ __launch_bounds__(256)
void bn_relu_kernel(float* __restrict__ out,
                    const float* __restrict__ gamma,
                    const float* __restrict__ beta,
                    const float* __restrict__ mean,
                    const float* __restrict__ var)
{
    const int total4 = NOUT * C / 4;
    int idx = blockIdx.x * blockDim.x + threadIdx.x;
    if (idx >= total4) return;
    const int c0 = (idx * 4) & (C - 1);
    float sc[4], sh[4];
    #pragma unroll
    for (int j = 0; j < 4; ++j) {
        const int c  = c0 + j;
        const float s = gamma[c] * rsqrtf(var[c] + EPS);
        sc[j] = s;
        sh[j] = beta[c] - mean[c] * s;
    }
    float4* p = reinterpret_cast<float4*>(out) + idx;
    float4 v = *p;
    v.x = fmaf(v.x, sc[0], sh[0]); v.x = v.x > 0.f ? v.x : 0.f;
    v.y = fmaf(v.y, sc[1], sh[1]); v.y = v.y > 0.f ? v.y : 0.f;
    v.z = fmaf(v.z, sc[2], sh[2]); v.z = v.z > 0.f ? v.z : 0.f;
    v.w = fmaf(v.w, sc[3], sh[3]); v.w = v.w > 0.f ? v.w : 0.f;
    *p = v;
}

// ---------------------------------------------------------------------------
extern "C" void kernel_launch(void* const* d_in, const int* in_sizes, int n_in,
                              void* d_out, int out_size, void* d_ws, size_t ws_size,
                              hipStream_t stream) {
    const float* feats   = (const float*)d_in[0];
    const float* weight  = (const float*)d_in[1];
    const int*   in_idx  = (const int*)  d_in[2];
    const int*   out_idx = (const int*)  d_in[3];
    const float* gamma   = (const float*)d_in[4];
    const float* beta    = (const float*)d_in[5];
    const float* rmean   = (const float*)d_in[6];
    const float* rvar    = (const float*)d_in[7];
    float* out = (float*)d_out;

    auto align = [](size_t x) { return (x + 255) & ~(size_t)255; };

    // Pick largest kpg in [5,16] whose buffers fit (lk payload field = 4 bits).
    int kpg = 0, G = 0;
    size_t oBin = 0, oBcnt = 0, oBoff = 0, oBcur = 0, oFb = 0, oWb = 0, oP = 0;
    for (int t = 16; t >= 5; --t) {
        int g  = (KOFF + t - 1) / t;
        int gb = g * NBUK;
        size_t a = 0;
        size_t bi = a; a += align((size_t)NPAIR * 4);             // binned payloads
        size_t bc = a; a += align((size_t)gb * 4);                // bcnt
        size_t bo = a; a += align((size_t)(gb + 1) * 4);          // boff
        size_t bu = a; a += align((size_t)gb * 4);                // bcur
        size_t fb = a; a += align((size_t)NIN * C * 2);           // feats bf16
        size_t wb = a; a += align((size_t)KOFF * C * C * 2);      // weight bf16
        size_t q_ = a; a += align((size_t)t * NIN * C * 2);       // P_chunk bf16
        if (a <= ws_size) {
            kpg = t; G = g;
            oBin = bi; oBcnt = bc; oBoff = bo; oBcur = bu; oFb = fb; oWb = wb; oP = q_;
            break;
        }
    }

    if (kpg == 0) {
        hipMemsetAsync(out, 0, (size_t)out_size * sizeof(float), stream);
        dim3 grid(512, KOFF);
        conv_scatter_kernel<<<grid, 256, 0, stream>>>(feats, weight, in_idx, out_idx, out);
        const int total4 = NOUT * C / 4;
        bn_relu_kernel<<<(total4 + 255) / 256, 256, 0, stream>>>(out, gamma, beta, rmean, rvar);
        return;
    }

    const int GB = G * NBUK;
    char* ws = (char*)d_ws;
    uint32_t* binned = (uint32_t*)(ws + oBin);
    int* bcnt = (int*)(ws + oBcnt);
    int* boff = (int*)(ws + oBoff);
    int* bcur = (int*)(ws + oBcur);
    ushort* featsb  = (ushort*)(ws + oFb);
    ushort* weightb = (ushort*)(ws + oWb);
    ushort* P       = (ushort*)(ws + oP);

    // --- bf16 conversions ---
    {
        int n8f = NIN * C / 8;
        cvt_bf16_kernel<<<(n8f + 255) / 256, 256, 0, stream>>>(feats, featsb, n8f);
        int n8w = KOFF * C * C / 8;
        cvt_bf16_kernel<<<(n8w + 255) / 256, 256, 0, stream>>>(weight, weightb, n8w);
    }

    // --- Bucket binning ---
    hipMemsetAsync(bcnt, 0, (size_t)GB * sizeof(int), stream);
    {
        int nbC = (NPAIR + IPB_C - 1) / IPB_C;
        bin_count_kernel<<<nbC, 256, 0, stream>>>(out_idx, bcnt, kpg, GB);
        bucket_scan_kernel<<<1, 1024, 0, stream>>>(bcnt, boff, bcur, GB);
        int nbF = (NPAIR + IPB_F - 1) / IPB_F;
        bin_fill_kernel<<<nbF, 256, 0, stream>>>(in_idx, out_idx, bcur, binned, kpg, GB);
    }

    // --- Per-group: MFMA GEMM chunk, then half-bucket gather into out ---
    for (int g = 0; g < G; ++g) {
        const int k0   = g * kpg;
        const int kcnt = (k0 + kpg <= KOFF) ? kpg : (KOFF - k0);

        dim3 grid(128, kcnt);
        gemm_mfma_kernel<<<grid, 256, 0, stream>>>(featsb, weightb, P, k0);

        dim3 ggrid(NBUK, 2);
        gather_bucket_kernel<<<ggrid, 256, 0, stream>>>(
            (const uint2*)P, binned, boff, g * NBUK,
            gamma, beta, rmean, rvar, out,
            /*accumulate=*/(g > 0), /*finalize=*/(g == G - 1));
    }
}